// Round 7
// baseline (249.698 us; speedup 1.0000x reference)
//
#include <hip/hip_runtime.h>

// 4-qubit circuit, B=2^20, ONE fused kernel, spill-free (SPT=2, VGPR<128).
// out_w(x) = sum_{a,b in 9x9} K_w[b][a] * F01[a](x0,x1) * F23[b](x2,x3)
// F01/F23: outer products of per-qubit basis {1, cos(pi*x_q), sin(pi*x_q)}.
// K (4x81, rows padded to 12) depends only on weights; each block recomputes
// it into LDS (phases validated R1-R5), then processes 2 samples/thread.
// Wire w <-> bit (3-w) of flat state index j (wire 0 = MSB).

#define SPT 2  // samples per thread — keeps basis arrays (2x16 floats) in VGPRs

__global__ __launch_bounds__(256, 4) void qc_fused(const float4* __restrict__ x4,
                                                   float4* __restrict__ out4,
                                                   const float* __restrict__ w) {
    __shared__ float sUr[16][16], sUi[16][16];     // [j][k]
    __shared__ float sA[4][16][16];                // [w][k][l]
    __shared__ float sK[4 * 9 * 12];               // [w][b][a], rows padded to 12

    const int tid = threadIdx.x;

    // ---- Phase 1: U columns via wave shuffles (thread k=tid>>4, j=tid&15) ---
    {
        const int k = tid >> 4;
        const int j = tid & 15;
        float vr = (j == k) ? 1.f : 0.f;
        float vi = 0.f;
#pragma unroll
        for (int d = 0; d < 2; ++d) {
#pragma unroll
            for (int p = 0; p < 4; ++p) {           // CNOT ring
                const int mc = 8 >> p;
                const int mt = 8 >> ((p + 1) & 3);
                const float ur = __shfl_xor(vr, mt);
                const float ui = __shfl_xor(vi, mt);
                if (j & mc) { vr = ur; vi = ui; }
            }
#pragma unroll
            for (int i = 0; i < 4; ++i) {
                const int mw = 8 >> i;
                const float th = 0.5f * w[(d * 4 + i) * 2 + 0];
                const float c = __cosf(th), s = __sinf(th);
                const float uyr = __shfl_xor(vr, mw);
                const float uyi = __shfl_xor(vi, mw);
                const float sgn = (j & mw) ? s : -s;
                vr = fmaf(sgn, uyr, c * vr);
                vi = fmaf(sgn, uyi, c * vi);
                const float ph = 0.5f * w[(d * 4 + i) * 2 + 1];
                const float cp = __cosf(ph), sp = __sinf(ph);
                const float pim = (j & mw) ? sp : -sp;
                const float t = cp * vr - pim * vi;
                vi = fmaf(cp, vi, pim * vr);
                vr = t;
            }
        }
        sUr[j][k] = vr;
        sUi[j][k] = vi;
    }
    __syncthreads();

    // ---- Phase 2: A_w[k][l] = sum_j sign_w(j)(Ur[j][k]Ur[j][l]+Ui[j][k]Ui[j][l])
    {
        const int k = tid >> 4, l = tid & 15;
        float g[16];
#pragma unroll
        for (int j = 0; j < 16; ++j)
            g[j] = sUr[j][k] * sUr[j][l] + sUi[j][k] * sUi[j][l];
#pragma unroll
        for (int w4 = 0; w4 < 4; ++w4) {
            float a = 0.f;
#pragma unroll
            for (int j = 0; j < 16; ++j)
                a += ((j >> (3 - w4)) & 1) ? -g[j] : g[j];
            sA[w4][k][l] = a;
        }
    }
    __syncthreads();

    // ---- Phase 3: K[w][a][b] = (1/16) sum of +/- A_w[k][l] -----------------
#pragma unroll
    for (int t0 = tid; t0 < 324; t0 += 256) {
        const int w4 = t0 / 81, r = t0 % 81;
        const int bb = r / 9, aa = r % 9;
        const int al[4] = { aa / 3, aa % 3, bb / 3, bb % 3 };
        float acc = 0.f;
#pragma unroll
        for (int t = 0; t < 16; ++t) {
            int k = 0, l = 0;
            float sgn = 1.f;
#pragma unroll
            for (int q = 0; q < 4; ++q) {
                const int alpha = al[q];
                const int c = (t >> q) & 1;
                int bk, bl;
                if (alpha == 2) { bk = c; bl = c ^ 1; }
                else           { bk = c; bl = c; if (alpha == 1 && c) sgn = -sgn; }
                k |= bk << (3 - q);
                l |= bl << (3 - q);
            }
            acc += sgn * sA[w4][k][l];
        }
        sK[(w4 * 9 + bb) * 12 + aa] = acc * 0.0625f;
    }
    __syncthreads();

    // ---- Main: 2 samples/thread; K rows = uniform LDS broadcast -------------
    const int base = blockIdx.x * (256 * SPT) + tid;

    float f01[SPT][8], f23[SPT][8];
#pragma unroll
    for (int s = 0; s < SPT; ++s) {
        const float4 xv = x4[base + 256 * s];
        // sin(pi*x) = v_sin(x/2 rev), cos likewise (validated R4).
        float S0, C0, S1, C1, S2, C2, S3, C3;
        const float h0 = 0.5f * xv.x, h1 = 0.5f * xv.y;
        const float h2 = 0.5f * xv.z, h3 = 0.5f * xv.w;
        asm("v_sin_f32 %0, %1" : "=v"(S0) : "v"(h0));
        asm("v_cos_f32 %0, %1" : "=v"(C0) : "v"(h0));
        asm("v_sin_f32 %0, %1" : "=v"(S1) : "v"(h1));
        asm("v_cos_f32 %0, %1" : "=v"(C1) : "v"(h1));
        asm("v_sin_f32 %0, %1" : "=v"(S2) : "v"(h2));
        asm("v_cos_f32 %0, %1" : "=v"(C2) : "v"(h2));
        asm("v_sin_f32 %0, %1" : "=v"(S3) : "v"(h3));
        asm("v_cos_f32 %0, %1" : "=v"(C3) : "v"(h3));
        f01[s][0] = C1;       f01[s][1] = S1;
        f01[s][2] = C0;       f01[s][3] = C0 * C1;  f01[s][4] = C0 * S1;
        f01[s][5] = S0;       f01[s][6] = S0 * C1;  f01[s][7] = S0 * S1;
        f23[s][0] = C3;       f23[s][1] = S3;
        f23[s][2] = C2;       f23[s][3] = C2 * C3;  f23[s][4] = C2 * S3;
        f23[s][5] = S2;       f23[s][6] = S2 * C3;  f23[s][7] = S2 * S3;
    }

    float o[SPT][4];
#pragma unroll
    for (int W = 0; W < 4; ++W) {
#pragma unroll
        for (int b = 0; b < 9; ++b) {
            const float4 k0 = *reinterpret_cast<const float4*>(&sK[(W * 9 + b) * 12]);
            const float4 k1 = *reinterpret_cast<const float4*>(&sK[(W * 9 + b) * 12 + 4]);
            const float  k8 = sK[(W * 9 + b) * 12 + 8];
#pragma unroll
            for (int s = 0; s < SPT; ++s) {
                float tt = k0.x;
                tt = fmaf(k0.y, f01[s][0], tt);
                tt = fmaf(k0.z, f01[s][1], tt);
                tt = fmaf(k0.w, f01[s][2], tt);
                tt = fmaf(k1.x, f01[s][3], tt);
                tt = fmaf(k1.y, f01[s][4], tt);
                tt = fmaf(k1.z, f01[s][5], tt);
                tt = fmaf(k1.w, f01[s][6], tt);
                tt = fmaf(k8,   f01[s][7], tt);
                if (b == 0) o[s][W] = tt;
                else        o[s][W] = fmaf(tt, f23[s][b - 1], o[s][W]);
            }
        }
    }

#pragma unroll
    for (int s = 0; s < SPT; ++s)
        out4[base + 256 * s] = make_float4(o[s][0], o[s][1], o[s][2], o[s][3]);
}

extern "C" void kernel_launch(void* const* d_in, const int* in_sizes, int n_in,
                              void* d_out, int out_size, void* d_ws, size_t ws_size,
                              hipStream_t stream) {
    const float* x = (const float*)d_in[0];
    const float* w = (const float*)d_in[1];
    const int B = in_sizes[0] / 4;  // 1,048,576

    hipLaunchKernelGGL(qc_fused, dim3(B / (256 * SPT)), dim3(256), 0, stream,
                       (const float4*)x, (float4*)d_out, w);
}

// Round 8
// 25.009 us; speedup vs baseline: 9.9842x; 9.9842x over previous
//
#include <hip/hip_runtime.h>

// 4-qubit circuit, B=2^20, ONE fused kernel, K-in-registers.
// out_w(x) = sum_{a,b in 9x9} K_w[b][a] * F01[a](x0,x1) * F23[b](x2,x3)
// F01/F23: outer products of per-qubit basis {1, cos(pi*x_q), sin(pi*x_q)}.
// K (4x81) depends only on weights; each block recomputes it into LDS
// (phases validated R1-R6). Then: lane L owns (sample = base + (L>>2),
// W = L&3) and keeps its 81 K_W coefficients in VGPRs across a 16-iter
// sample loop. No per-sample K loads; coalesced float4 x-loads (4-way
// replicated) and coalesced float stores.
// Wire w <-> bit (3-w) of flat state index j (wire 0 = MSB).

__global__ void qc_fused(const float4* __restrict__ x4,
                         float* __restrict__ outf,
                         const float* __restrict__ w) {
    __shared__ float sUr[16][16], sUi[16][16];     // [j][k]
    __shared__ float sA[4][16][16];                // [w][k][l]
    __shared__ float sK[4 * 9 * 12];               // [w][b][a], rows padded to 12

    const int tid = threadIdx.x;

    // ---- Phase 1: U columns via wave shuffles (thread k=tid>>4, j=tid&15) ---
    {
        const int k = tid >> 4;
        const int j = tid & 15;
        float vr = (j == k) ? 1.f : 0.f;
        float vi = 0.f;
#pragma unroll
        for (int d = 0; d < 2; ++d) {
#pragma unroll
            for (int p = 0; p < 4; ++p) {           // CNOT ring
                const int mc = 8 >> p;
                const int mt = 8 >> ((p + 1) & 3);
                const float ur = __shfl_xor(vr, mt);
                const float ui = __shfl_xor(vi, mt);
                if (j & mc) { vr = ur; vi = ui; }
            }
#pragma unroll
            for (int i = 0; i < 4; ++i) {
                const int mw = 8 >> i;
                const float th = 0.5f * w[(d * 4 + i) * 2 + 0];
                const float c = __cosf(th), s = __sinf(th);
                const float uyr = __shfl_xor(vr, mw);
                const float uyi = __shfl_xor(vi, mw);
                const float sgn = (j & mw) ? s : -s;
                vr = fmaf(sgn, uyr, c * vr);
                vi = fmaf(sgn, uyi, c * vi);
                const float ph = 0.5f * w[(d * 4 + i) * 2 + 1];
                const float cp = __cosf(ph), sp = __sinf(ph);
                const float pim = (j & mw) ? sp : -sp;
                const float t = cp * vr - pim * vi;
                vi = fmaf(cp, vi, pim * vr);
                vr = t;
            }
        }
        sUr[j][k] = vr;
        sUi[j][k] = vi;
    }
    __syncthreads();

    // ---- Phase 2: A_w[k][l] = sum_j sign_w(j)(Ur[j][k]Ur[j][l]+Ui[j][k]Ui[j][l])
    {
        const int k = tid >> 4, l = tid & 15;
        float g[16];
#pragma unroll
        for (int j = 0; j < 16; ++j)
            g[j] = sUr[j][k] * sUr[j][l] + sUi[j][k] * sUi[j][l];
#pragma unroll
        for (int w4 = 0; w4 < 4; ++w4) {
            float a = 0.f;
#pragma unroll
            for (int j = 0; j < 16; ++j)
                a += ((j >> (3 - w4)) & 1) ? -g[j] : g[j];
            sA[w4][k][l] = a;
        }
    }
    __syncthreads();

    // ---- Phase 3: K[w][a][b] = (1/16) sum of +/- A_w[k][l] -----------------
#pragma unroll
    for (int t0 = tid; t0 < 324; t0 += 256) {
        const int w4 = t0 / 81, r = t0 % 81;
        const int bb = r / 9, aa = r % 9;
        const int al[4] = { aa / 3, aa % 3, bb / 3, bb % 3 };
        float acc = 0.f;
#pragma unroll
        for (int t = 0; t < 16; ++t) {
            int k = 0, l = 0;
            float sgn = 1.f;
#pragma unroll
            for (int q = 0; q < 4; ++q) {
                const int alpha = al[q];
                const int c = (t >> q) & 1;
                int bk, bl;
                if (alpha == 2) { bk = c; bl = c ^ 1; }
                else           { bk = c; bl = c; if (alpha == 1 && c) sgn = -sgn; }
                k |= bk << (3 - q);
                l |= bl << (3 - q);
            }
            acc += sgn * sA[w4][k][l];
        }
        sK[(w4 * 9 + bb) * 12 + aa] = acc * 0.0625f;
    }
    __syncthreads();

    // ---- One-time: lane's K_W (81 floats) from LDS into registers ----------
    const int W = tid & 3;
    float K[81];
#pragma unroll
    for (int b = 0; b < 9; ++b)
#pragma unroll
        for (int a = 0; a < 9; ++a)
            K[b * 9 + a] = sK[(W * 9 + b) * 12 + a];

    // ---- Main loop: 16 iters; 4 lanes per sample -----------------------------
    const int sbase = blockIdx.x * 1024;   // samples per block = 1024
    const int soff  = tid >> 2;            // 0..63

#pragma unroll 1
    for (int i = 0; i < 16; ++i) {
        const int s = sbase + i * 64 + soff;
        const float4 xv = x4[s];

        // sin(pi*x) = v_sin(x/2 rev), cos likewise (validated R4).
        float S0, C0, S1, C1, S2, C2, S3, C3;
        const float h0 = 0.5f * xv.x, h1 = 0.5f * xv.y;
        const float h2 = 0.5f * xv.z, h3 = 0.5f * xv.w;
        asm("v_sin_f32 %0, %1" : "=v"(S0) : "v"(h0));
        asm("v_cos_f32 %0, %1" : "=v"(C0) : "v"(h0));
        asm("v_sin_f32 %0, %1" : "=v"(S1) : "v"(h1));
        asm("v_cos_f32 %0, %1" : "=v"(C1) : "v"(h1));
        asm("v_sin_f32 %0, %1" : "=v"(S2) : "v"(h2));
        asm("v_cos_f32 %0, %1" : "=v"(C2) : "v"(h2));
        asm("v_sin_f32 %0, %1" : "=v"(S3) : "v"(h3));
        asm("v_cos_f32 %0, %1" : "=v"(C3) : "v"(h3));

        const float f1 = C1,      f2 = S1,      f3 = C0;
        const float f4 = C0 * C1, f5 = C0 * S1, f6 = S0;
        const float f7 = S0 * C1, f8 = S0 * S1;
        const float g1 = C3,      g2 = S3,      g3 = C2;
        const float g4 = C2 * C3, g5 = C2 * S3, g6 = S2;
        const float g7 = S2 * C3, g8 = S2 * S3;
        const float gm[8] = { g1, g2, g3, g4, g5, g6, g7, g8 };

        float acc = 0.f;
#pragma unroll
        for (int b = 0; b < 9; ++b) {
            float t = K[b * 9 + 0];
            t = fmaf(K[b * 9 + 1], f1, t);
            t = fmaf(K[b * 9 + 2], f2, t);
            t = fmaf(K[b * 9 + 3], f3, t);
            t = fmaf(K[b * 9 + 4], f4, t);
            t = fmaf(K[b * 9 + 5], f5, t);
            t = fmaf(K[b * 9 + 6], f6, t);
            t = fmaf(K[b * 9 + 7], f7, t);
            t = fmaf(K[b * 9 + 8], f8, t);
            acc = (b == 0) ? t : fmaf(t, gm[b - 1], acc);
        }

        outf[s * 4 + W] = acc;   // contiguous 256 floats per block-iter
    }
}

extern "C" void kernel_launch(void* const* d_in, const int* in_sizes, int n_in,
                              void* d_out, int out_size, void* d_ws, size_t ws_size,
                              hipStream_t stream) {
    const float* x = (const float*)d_in[0];
    const float* w = (const float*)d_in[1];
    const int B = in_sizes[0] / 4;  // 1,048,576

    hipLaunchKernelGGL(qc_fused, dim3(B / 1024), dim3(256), 0, stream,
                       (const float4*)x, (float*)d_out, w);
}